// Round 7
// baseline (89.163 us; speedup 1.0000x reference)
//
#include <hip/hip_runtime.h>
#include <hip/hip_bf16.h>
#include <cstdint>
#include <cstddef>

#define BB 32
#define SS 4096
#define DD 256
#define UU 256
#define BM 64
#define NCH (SS / BM)   // 64 chunks per batch

typedef __attribute__((ext_vector_type(8))) short short8;
typedef __attribute__((ext_vector_type(4))) float f32x4;

__device__ __forceinline__ unsigned short f2bf(float x) {
  union { float f; unsigned int u; } c; c.f = x;
  unsigned int r = c.u + 0x7FFFu + ((c.u >> 16) & 1u);
  return (unsigned short)(r >> 16);
}

// pack2(lo, hi) -> u32 [bf16(hi)<<16 | bf16(lo)], round-half-up
__device__ __forceinline__ unsigned int bfpack2(float lo, float hi) {
  union { float f; unsigned int u; } a, b;
  a.f = hi; b.f = lo;
  return __builtin_amdgcn_perm(a.u + 0x8000u, b.u + 0x8000u, 0x07060302u);
}

__device__ __forceinline__ short8 bfpack8(float4 f0, float4 f1) {
  union { unsigned int u[4]; short8 s; } r;
  r.u[0] = bfpack2(f0.x, f0.y);
  r.u[1] = bfpack2(f0.z, f0.w);
  r.u[2] = bfpack2(f1.x, f1.y);
  r.u[3] = bfpack2(f1.z, f1.w);
  return r.s;
}

// K1: posb[b][u] = position[b] @ W1[:,u] + b1[u] + b2[u]   (exact fp32)
__global__ void k_posproj(const float* __restrict__ pos, const float* __restrict__ W1,
                          const float* __restrict__ b1, const float* __restrict__ b2,
                          float* __restrict__ posb) {
  __shared__ float p[DD];
  int b = blockIdx.x, u = threadIdx.x;
  p[u] = pos[b * DD + u];
  __syncthreads();
  float acc = b1[u] + b2[u];
#pragma unroll 4
  for (int d = 0; d < DD; ++d) acc = fmaf(p[d], W1[(size_t)d * UU + u], acc);
  posb[b * UU + u] = acc;
}

// K1b: w2t[u][d] = bf16(W2[d][u])  (tiled transpose)
__global__ void k_w2t(const float* __restrict__ W2, unsigned short* __restrict__ w2t) {
  __shared__ unsigned short tile[16][17];
  int di = blockIdx.x * 16, ui = blockIdx.y * 16;
  int t = threadIdx.x;
  int r = t >> 4, c = t & 15;
  tile[c][r] = f2bf(W2[(size_t)(di + r) * UU + ui + c]);
  __syncthreads();
  w2t[(size_t)(ui + r) * DD + di + c] = tile[r][c];
}

// K2 (fused): A staged once (full K), B triple-buffered gll with counted vmcnt.
// LDS: A [64 rows][32 octets 16B, phys = o^(row&31)]  = 32 KB  @ 0
//      B 3 x [256 u][4 octets 16B, phys = kg^((u>>1)&3)] = 48 KB @ 32768
__global__ __launch_bounds__(512, 4) void k_score_ctx(
    const float* __restrict__ options, const unsigned short* __restrict__ w2t,
    const float* __restrict__ posb, const float* __restrict__ V,
    const float* __restrict__ bvp, float* __restrict__ scores,
    float* __restrict__ part, float2* __restrict__ ml) {
  __shared__ __align__(16) unsigned char smem[81920];   // 80 KB
  unsigned char* const bufB = smem + 32768;

  const int tid = threadIdx.x;
  const int ch = blockIdx.x;            // 0..63
  const int b  = blockIdx.y;
  const int s0 = ch * BM;
  const int wid = tid >> 6, l = tid & 63;
  const int wr = wid >> 2;              // 0..1  (32-row half)
  const int wc = wid & 3;               // 0..3  (64-u quarter)
  const int il = l & 15, kg = l >> 4;

  const float* optb = options + ((size_t)b * SS + s0) * DD;

  // ---- A static stage: 64 rows x 256 k (fp32 -> bf16, swizzled) ----
  {
    const int arow = tid >> 3;          // 0..63
    const int acs  = tid & 7;
    const float* pa = optb + (size_t)arow * DD;
#pragma unroll
    for (int j = 0; j < 4; ++j) {
      int o = j * 8 + acs;              // logical 16B-octet 0..31
      float4 f0 = *(const float4*)(pa + o * 8);
      float4 f1 = *(const float4*)(pa + o * 8 + 4);
      *(short8*)(smem + arow * 512 + ((o ^ (arow & 31)) << 4)) = bfpack8(f0, f1);
    }
  }

  // ---- B gll lane geometry (physical slot -> inverse-swizzled source) ----
  int uB0, uB1;
  const unsigned short *srcB0, *srcB1;
  {
    int p0 = (wid * 2) * 64 + l;
    int p1 = p0 + 64;
    uB0 = p0 >> 2; uB1 = p1 >> 2;
    int s0b = (p0 & 3) ^ ((uB0 >> 1) & 3);
    int s1b = (p1 & 3) ^ ((uB1 >> 1) & 3);
    srcB0 = w2t + (size_t)uB0 * DD + s0b * 8;
    srcB1 = w2t + (size_t)uB1 * DD + s1b * 8;
  }

#define GLLB(T, SLOT)                                                            \
  {                                                                              \
    __builtin_amdgcn_global_load_lds(                                            \
        (const __attribute__((address_space(1))) void*)(srcB0 + (T) * 32),       \
        (__attribute__((address_space(3))) void*)(bufB + (SLOT) * 16384 + (wid * 2) * 1024), \
        16, 0, 0);                                                               \
    __builtin_amdgcn_global_load_lds(                                            \
        (const __attribute__((address_space(1))) void*)(srcB1 + (T) * 32),       \
        (__attribute__((address_space(3))) void*)(bufB + (SLOT) * 16384 + (wid * 2 + 1) * 1024), \
        16, 0, 0);                                                               \
  }

  // ---- MFMA read offsets ----
  int abase[2], as[2];
#pragma unroll
  for (int mi = 0; mi < 2; ++mi) {
    int r = wr * 32 + mi * 16 + il;
    abase[mi] = r * 512;
    as[mi] = r & 31;
  }
  int boffs[4];
#pragma unroll
  for (int ni = 0; ni < 4; ++ni) {
    int u = wc * 64 + ni * 16 + il;
    boffs[ni] = u * 64 + ((kg ^ ((u >> 1) & 3)) << 4);
  }

  f32x4 acc[2][4];
#pragma unroll
  for (int mi = 0; mi < 2; ++mi)
#pragma unroll
    for (int ni = 0; ni < 4; ++ni) {
      f32x4 z = {0.f, 0.f, 0.f, 0.f};
      acc[mi][ni] = z;
    }

  // ---- prologue: B tiles 0,1 in flight; drain tile 0 + A ds_writes ----
  GLLB(0, 0);
  GLLB(1, 1);
  asm volatile("s_waitcnt vmcnt(2) lgkmcnt(0)" ::: "memory");
  __builtin_amdgcn_sched_barrier(0);
  __builtin_amdgcn_s_barrier();

  // ---- K-loop: 8 iters of BK=32; only vmem = 2 gll/iter -> exact vmcnt ----
#pragma unroll
  for (int t = 0; t < 8; ++t) {
    if (t < 6) GLLB(t + 2, (t + 2) % 3);
    const unsigned char* bC = bufB + (t % 3) * 16384;
    short8 af[2];
#pragma unroll
    for (int mi = 0; mi < 2; ++mi)
      af[mi] = *(const short8*)(smem + abase[mi] + (((4 * t + kg) ^ as[mi]) << 4));
    __builtin_amdgcn_s_setprio(1);
#pragma unroll
    for (int ni = 0; ni < 4; ++ni) {
      short8 bf = *(const short8*)(bC + boffs[ni]);
      acc[0][ni] = __builtin_amdgcn_mfma_f32_16x16x32_bf16(af[0], bf, acc[0][ni], 0, 0, 0);
      acc[1][ni] = __builtin_amdgcn_mfma_f32_16x16x32_bf16(af[1], bf, acc[1][ni], 0, 0, 0);
    }
    __builtin_amdgcn_s_setprio(0);
    if (t < 6) {
      asm volatile("s_waitcnt vmcnt(2)" ::: "memory");   // leave tile t+2 in flight
    } else if (t == 6) {
      asm volatile("s_waitcnt vmcnt(0)" ::: "memory");   // drain last tile
    }
    if (t < 7) {
      __builtin_amdgcn_sched_barrier(0);
      __builtin_amdgcn_s_barrier();
    }
  }
#undef GLLB

  __syncthreads();

  // ---- epilogue overlay (A/B tiles dead) ----
  float (*red)[4] = (float (*)[4])smem;                 // [64][4]  (1 KB)
  float* pbuf     = (float*)(smem + 1024);              // [64]
  float4* pr      = (float4*)(smem + 2048);             // [512]    (8 KB)

  float part_r[2][4];
#pragma unroll
  for (int mi = 0; mi < 2; ++mi)
#pragma unroll
    for (int r = 0; r < 4; ++r) part_r[mi][r] = 0.f;

#pragma unroll
  for (int ni = 0; ni < 4; ++ni) {
    int u = wc * 64 + ni * 16 + il;
    float pv = posb[b * UU + u];
    float vv = V[u];
#pragma unroll
    for (int mi = 0; mi < 2; ++mi)
#pragma unroll
      for (int r = 0; r < 4; ++r) {
        float x = acc[mi][ni][r] + pv;
        float tnh = 1.f - __fdividef(2.f, __expf(2.f * x) + 1.f);
        part_r[mi][r] = fmaf(tnh, vv, part_r[mi][r]);
      }
  }
#pragma unroll
  for (int mi = 0; mi < 2; ++mi)
#pragma unroll
    for (int r = 0; r < 4; ++r) {
      float p = part_r[mi][r];
      p += __shfl_xor(p, 1);
      p += __shfl_xor(p, 2);
      p += __shfl_xor(p, 4);
      p += __shfl_xor(p, 8);
      part_r[mi][r] = p;
    }
  if (il == 0) {
#pragma unroll
    for (int mi = 0; mi < 2; ++mi)
#pragma unroll
      for (int r = 0; r < 4; ++r)
        red[wr * 32 + mi * 16 + kg * 4 + r][wc] = part_r[mi][r];
  }
  __syncthreads();

  // softmax stats over 64 rows (wave 0, 1 row/lane)
  const float bvv = bvp[0];
  if (tid < 64) {
    float4 r0 = *(const float4*)red[tid];
    float sv = r0.x + r0.y + r0.z + r0.w + bvv;
    scores[(size_t)b * SS + s0 + tid] = sv;
    float m = sv;
#pragma unroll
    for (int off = 32; off >= 1; off >>= 1) m = fmaxf(m, __shfl_xor(m, off));
    float p = __expf(sv - m);
    float ls = p;
#pragma unroll
    for (int off = 32; off >= 1; off >>= 1) ls += __shfl_xor(ls, off);
    pbuf[tid] = p;
    if (tid == 0) ml[b * NCH + ch] = make_float2(m, ls);
  }
  __syncthreads();

  // partial context: fp32 re-read of the tile (L3-hot)
  {
    int rg = tid >> 6;
    int d4 = (tid & 63) << 2;
    float a0 = 0.f, a1 = 0.f, a2 = 0.f, a3 = 0.f;
#pragma unroll
    for (int i = 0; i < 8; ++i) {
      int s = i * 8 + rg;
      const float4 o = *(const float4*)(optb + (size_t)s * DD + d4);
      float w = pbuf[s];
      a0 = fmaf(w, o.x, a0); a1 = fmaf(w, o.y, a1);
      a2 = fmaf(w, o.z, a2); a3 = fmaf(w, o.w, a3);
    }
    pr[tid] = make_float4(a0, a1, a2, a3);
  }
  __syncthreads();
  if (tid < 64) {
    float4 o = pr[tid];
#pragma unroll
    for (int g = 1; g < 8; ++g) {
      float4 v = pr[g * 64 + tid];
      o.x += v.x; o.y += v.y; o.z += v.z; o.w += v.w;
    }
    *(float4*)&part[(((size_t)b * NCH + ch) * DD) + (tid << 2)] = o;
  }
}

// K3: per batch — combine 64 chunk partials, emit context + weights
__global__ __launch_bounds__(256) void k_final(
    const float* __restrict__ scores, const float* __restrict__ part,
    const float2* __restrict__ ml, float* __restrict__ ctx,
    float* __restrict__ wgt) {
  __shared__ float ms[NCH], lsh[NCH];
  int b = blockIdx.x, t = threadIdx.x;
  if (t < NCH) { float2 v = ml[b * NCH + t]; ms[t] = v.x; lsh[t] = v.y; }
  __syncthreads();
  float gm = ms[0];
#pragma unroll
  for (int i = 1; i < NCH; ++i) gm = fmaxf(gm, ms[i]);
  float gs = 0.f;
#pragma unroll
  for (int i = 0; i < NCH; ++i) gs += lsh[i] * __expf(ms[i] - gm);
  float inv = 1.f / gs;
  float acc = 0.f;
#pragma unroll 4
  for (int i = 0; i < NCH; ++i)
    acc += part[((size_t)b * NCH + i) * DD + t] * __expf(ms[i] - gm);
  ctx[b * DD + t] = acc * inv;
  const float* sb = scores + (size_t)b * SS;
  float* wb = wgt + (size_t)b * SS;
#pragma unroll 4
  for (int i = 0; i < 16; ++i) {
    int s = i * 256 + t;
    wb[s] = __expf(sb[s] - gm) * inv;
  }
}

extern "C" void kernel_launch(void* const* d_in, const int* in_sizes, int n_in,
                              void* d_out, int out_size, void* d_ws, size_t ws_size,
                              hipStream_t stream) {
  const float* position = (const float*)d_in[0];
  const float* options  = (const float*)d_in[1];
  const float* W1 = (const float*)d_in[2];
  const float* b1 = (const float*)d_in[3];
  const float* W2 = (const float*)d_in[4];
  const float* b2 = (const float*)d_in[5];
  const float* V  = (const float*)d_in[6];
  const float* bv = (const float*)d_in[7];

  float* out = (float*)d_out;
  float* ctx_out = out;              // [32,256]
  float* wgt_out = out + BB * DD;    // [32,4096]

  char* ws = (char*)d_ws;
  float* posb         = (float*)ws;                          // 32 KB
  unsigned short* w2t = (unsigned short*)(ws + 32 * 1024);   // 128 KB
  float* scores       = (float*)(ws + 160 * 1024);           // 512 KB
  float* part         = (float*)(ws + 672 * 1024);           // 2 MB
  float2* ml          = (float2*)(ws + 672 * 1024 + 2 * 1024 * 1024); // 16 KB

  k_posproj<<<BB, 256, 0, stream>>>(position, W1, b1, b2, posb);
  k_w2t<<<dim3(16, 16), 256, 0, stream>>>(W2, w2t);
  k_score_ctx<<<dim3(NCH, BB), 512, 0, stream>>>(options, w2t, posb, V, bv,
                                                 scores, part, ml);
  k_final<<<BB, 256, 0, stream>>>(scores, part, ml, ctx_out, wgt_out);
}